// Round 13
// baseline (30.635 us; speedup 1.0000x reference)
//
#include <hip/hip_runtime.h>

#define SENT (-3.402823466e38f)

typedef __attribute__((ext_vector_type(8))) short short8;
typedef __attribute__((ext_vector_type(4))) float floatx4;

// ws float offsets
#define OFF_QKP   0         // ushort[512][512]  qkp bf16 (1/sqrt(D) baked in)
#define OFF_AGG   131072    // ushort[512][512]  agg bf16
#define OFF_M2    262144    // ushort[256][768]  folded out-proj weights, bf16
#define OFF_B2    360448    // float[256]        bp + bv@Wp^T

__device__ __forceinline__ ushort f2b(float f) {          // RNE fp32->bf16
    uint u = __float_as_uint(f);
    u += 0x7FFFu + ((u >> 16) & 1u);
    return (ushort)(u >> 16);
}
__device__ __forceinline__ short8 pk8(float4 a, float4 b) {
    short8 r;
    r[0]=(short)f2b(a.x); r[1]=(short)f2b(a.y); r[2]=(short)f2b(a.z); r[3]=(short)f2b(a.w);
    r[4]=(short)f2b(b.x); r[5]=(short)f2b(b.y); r[6]=(short)f2b(b.z); r[7]=(short)f2b(b.w);
    return r;
}

// ---------------- K1: qkp (r9-proven MFMA path) + M2/b2 precompute ---------
// grid 161: b<128 qkp (rt32 x ct4); b<160 M2 fold (8-o tiles); b=160 b2.
__global__ __launch_bounds__(256, 4)
void k1_proj(const float* __restrict__ x, const float* __restrict__ Wq,
             const float* __restrict__ bq, const float* __restrict__ Wk,
             const float* __restrict__ Wv, const float* __restrict__ bv,
             const float* __restrict__ Wp, const float* __restrict__ bp,
             ushort* __restrict__ qkp, ushort* __restrict__ M2u,
             float* __restrict__ b2f) {
    __shared__ float smem[16*264 + 16*66];
    int tid = threadIdx.x;
    int b = blockIdx.x;

    if (b < 128) {   // ---- qkp: q = x@Wq^T + bq (MFMA), then @WkE * 1/sqrt(D)
        float (*xL)[264] = (float(*)[264])smem;
        float (*qls)[66] = (float(*)[66])(smem + 16*264);
        int w = tid >> 6, lane = tid & 63, g = lane >> 4, r = lane & 15;
        int rt = b >> 2, ct = b & 3;
        int r0 = rt*16, c0 = ct*64, h0 = ct*2;

        #pragma unroll
        for (int it = 0; it < 4; ++it) {     // stage x[16][256]
            int fid = (tid + 256*it)*4;
            int rr = fid >> 8, k = fid & 255;
            *(float4*)&xL[rr][k] = *(const float4*)&x[(size_t)(r0+rr)*256 + k];
        }
        __syncthreads();

        int c = c0 + w*16 + r;
        const float* Wrow = Wq + (size_t)c*256;
        floatx4 acc = {0.f,0.f,0.f,0.f};
        #pragma unroll
        for (int kt = 0; kt < 8; ++kt) {
            int k0 = kt*32 + g*8;
            short8 af = pk8(*(float4*)&xL[r][k0], *(float4*)&xL[r][k0+4]);
            short8 bf = pk8(*(const float4*)&Wrow[k0], *(const float4*)&Wrow[k0+4]);
            acc = __builtin_amdgcn_mfma_f32_16x16x32_bf16(af, bf, acc, 0,0,0);
        }
        float bb = bq[c];
        #pragma unroll
        for (int i = 0; i < 4; ++i)
            qls[4*g + i][w*16 + r] = acc[i] + bb;
        __syncthreads();

        int rr = tid >> 4, es = tid & 15;        // row, e-quad
        float a0[4] = {0,0,0,0}, a1[4] = {0,0,0,0};
        const float* wk0 = Wk + (size_t)(h0*32)*320 + 256 + es*4;
        const float* wk1 = Wk + (size_t)((h0+1)*32)*320 + 256 + es*4;
        #pragma unroll 8
        for (int d = 0; d < 32; ++d) {
            float q0 = qls[rr][d];
            float q1 = qls[rr][32 + d];
            float4 w0 = *(const float4*)&wk0[(size_t)d*320];
            float4 w1 = *(const float4*)&wk1[(size_t)d*320];
            a0[0]+=q0*w0.x; a0[1]+=q0*w0.y; a0[2]+=q0*w0.z; a0[3]+=q0*w0.w;
            a1[0]+=q1*w1.x; a1[1]+=q1*w1.y; a1[2]+=q1*w1.z; a1[3]+=q1*w1.w;
        }
        const float s = 0.17677669529663687f;    // 1/sqrt(32)
        ushort4 u0, u1;
        u0.x=f2b(a0[0]*s); u0.y=f2b(a0[1]*s); u0.z=f2b(a0[2]*s); u0.w=f2b(a0[3]*s);
        u1.x=f2b(a1[0]*s); u1.y=f2b(a1[1]*s); u1.z=f2b(a1[2]*s); u1.w=f2b(a1[3]*s);
        size_t base = (size_t)(r0 + rr)*512;
        *(ushort4*)&qkp[base + h0*64 + es*4]     = u0;
        *(ushort4*)&qkp[base + (h0+1)*64 + es*4] = u1;

    } else if (b < 160) {   // ---- M2 fold: 8-o tile. Wave-uniform LDS Wp rows.
        float (*WpL)[256] = (float(*)[256])smem;
        int ot = b - 128, o0 = ot*8;
        #pragma unroll
        for (int it = 0; it < 2; ++it) {   // stage Wp[8][256]
            int fid = (tid + 256*it)*4;
            int oo = fid >> 8, cc = fid & 255;
            *(float4*)&WpL[oo][cc] = *(const float4*)&Wp[(size_t)(o0+oo)*256 + cc];
        }
        __syncthreads();
        {   // left: M2[o][k] = sum_c Wvn[c][k]*Wp[o][c]; thread = k
            float acc[8] = {0,0,0,0,0,0,0,0};
            for (int c = 0; c < 256; ++c) {
                float wv = Wv[(size_t)c*320 + tid];       // coalesced
                #pragma unroll
                for (int oo = 0; oo < 8; ++oo)
                    acc[oo] += wv * WpL[oo][c];           // wave-uniform
            }
            #pragma unroll
            for (int oo = 0; oo < 8; ++oo)
                M2u[(size_t)(o0+oo)*768 + tid] = f2b(acc[oo]);
        }
        {   // right: M2[o][256+he] = sum_cc WvE[h*32+cc][e]*Wp[o][h*32+cc]
            #pragma unroll
            for (int hh = 0; hh < 2; ++hh) {
                int he = hh*256 + tid;
                int h = he >> 6, e = he & 63;
                float acc[8] = {0,0,0,0,0,0,0,0};
                #pragma unroll 8
                for (int cc = 0; cc < 32; ++cc) {
                    float wv = Wv[(size_t)(h*32+cc)*320 + 256 + e];
                    #pragma unroll
                    for (int oo = 0; oo < 8; ++oo)
                        acc[oo] += wv * WpL[oo][h*32+cc];
                }
                #pragma unroll
                for (int oo = 0; oo < 8; ++oo)
                    M2u[(size_t)(o0+oo)*768 + 256 + he] = f2b(acc[oo]);
            }
        }
    } else {   // ---- b2[o] = bp[o] + sum_c bv[c]*Wp[o][c]
        float acc = bp[tid];
        const float* wp = Wp + (size_t)tid*256;
        #pragma unroll 8
        for (int c = 0; c < 256; ++c) acc += bv[c] * wp[c];
        b2f[tid] = acc;
    }
}

// ---------------- K2: per-row attention (r12-proven, unchanged) ------------
__global__ __launch_bounds__(512, 4)
void k2_attn(const float* __restrict__ edge, const int* __restrict__ msk,
             const ushort* __restrict__ qkp, ushort* __restrict__ aggO) {
    __shared__ ushort edsA[128][72];
    __shared__ ushort qkpL[16][64];
    __shared__ float  attL[8][132];
    __shared__ ushort attT[16][136];
    __shared__ float  mval[128];
    int tid = threadIdx.x;
    int w = tid >> 6, lane = tid & 63, g = lane >> 4, r = lane & 15;
    int row = blockIdx.x;

    float4 ef[4];
    const float* eg = edge + (size_t)row*8192;
    #pragma unroll
    for (int it = 0; it < 4; ++it)
        ef[it] = *(const float4*)(eg + (size_t)(tid + 512*it)*4);

    if (tid < 256) {   // qkp stage (+ zero pad rows 8..15)
        ushort* qf = (ushort*)qkpL;
        *(uint*)&qf[tid*2]        = *(const uint*)&qkp[(size_t)row*512 + tid*2];
        *(uint*)&qf[512 + tid*2]  = 0u;
    }
    if (tid < 128) mval[tid] = (msk[(size_t)row*128 + tid] != 0) ? 1.0f : 0.0f;
    if (tid < 136) {
        #pragma unroll
        for (int hp = 8; hp < 16; ++hp) attT[hp][tid] = 0;
    }
    #pragma unroll
    for (int it = 0; it < 4; ++it) {   // edge -> bf16 LDS
        int fid = (tid + 512*it)*4;
        int j = fid >> 6, e = fid & 63;
        uint lo = (uint)f2b(ef[it].x) | ((uint)f2b(ef[it].y) << 16);
        uint hi = (uint)f2b(ef[it].z) | ((uint)f2b(ef[it].w) << 16);
        *(uint2*)&edsA[j][e] = make_uint2(lo, hi);
    }
    __syncthreads();

    {   // logits MFMA: D[j-local][h]; wave w = j-tile
        floatx4 acc = {0,0,0,0};
        #pragma unroll
        for (int kt = 0; kt < 2; ++kt) {
            short8 af = *(short8*)&edsA[w*16 + r][kt*32 + g*8];
            short8 bf = *(short8*)&qkpL[r][kt*32 + g*8];
            acc = __builtin_amdgcn_mfma_f32_16x16x32_bf16(af, bf, acc, 0,0,0);
        }
        if (r < 8) {
            #pragma unroll
            for (int i = 0; i < 4; ++i) {
                int j = w*16 + 4*g + i;
                attL[r][j] = (mval[j] > 0.5f) ? acc[i] : SENT;
            }
        }
    }
    __syncthreads();

    {   // softmax: wave w = head w
        float v0 = attL[w][lane];
        float v1 = attL[w][64 + lane];
        float mx = fmaxf(v0, v1);
        #pragma unroll
        for (int off = 32; off >= 1; off >>= 1) mx = fmaxf(mx, __shfl_xor(mx, off));
        float e0 = __expf(v0 - mx), e1 = __expf(v1 - mx);
        float smv = e0 + e1;
        #pragma unroll
        for (int off = 32; off >= 1; off >>= 1) smv += __shfl_xor(smv, off);
        float inv = 1.0f / smv;
        attT[w][lane]      = f2b(e0 * inv);
        attT[w][64 + lane] = f2b(e1 * inv);
    }
    __syncthreads();

    if (w < 4) {   // agg MFMA: D[h][e]; wave w = e-tile
        floatx4 acc = {0,0,0,0};
        #pragma unroll
        for (int kt = 0; kt < 4; ++kt) {
            short8 a2 = *(short8*)&attT[r][kt*32 + g*8];
            short8 b2;
            #pragma unroll
            for (int jj = 0; jj < 8; ++jj)
                b2[jj] = (short)edsA[kt*32 + g*8 + jj][w*16 + r];
            acc = __builtin_amdgcn_mfma_f32_16x16x32_bf16(a2, b2, acc, 0,0,0);
        }
        #pragma unroll
        for (int i = 0; i < 4; ++i) {
            int h = 4*g + i;
            if (h < 8)
                aggO[(size_t)row*512 + h*64 + w*16 + r] = f2b(acc[i]);
        }
    }
}

// ---------------- K3: out = x@M2l + agg@M2r + b2 (single GEMM, no LDS) -----
// grid 128 = rt(32) x ob(4), 256 thr. B-frags are pre-bf16 M2 rows.
__global__ __launch_bounds__(256, 4)
void k3_out(const float* __restrict__ x, const ushort* __restrict__ agg,
            const ushort* __restrict__ M2u, const float* __restrict__ b2f,
            float* __restrict__ out) {
    int tid = threadIdx.x;
    int w = tid >> 6, lane = tid & 63, g = lane >> 4, r = lane & 15;
    int rt = blockIdx.x >> 2, ob = blockIdx.x & 3;
    int r0 = rt*16, o0 = ob*64;

    int o = o0 + w*16 + r;
    const ushort* m2row = M2u + (size_t)o*768;
    const float*  xrow  = x + (size_t)(r0 + r)*256;
    const ushort* arow  = agg + (size_t)(r0 + r)*512;

    floatx4 acc = {0,0,0,0};
    #pragma unroll
    for (int kt = 0; kt < 8; ++kt) {        // x part, K=256
        int k0 = kt*32 + g*8;
        short8 af = pk8(*(const float4*)&xrow[k0], *(const float4*)&xrow[k0+4]);
        short8 bf = *(const short8*)&m2row[k0];
        acc = __builtin_amdgcn_mfma_f32_16x16x32_bf16(af, bf, acc, 0,0,0);
    }
    #pragma unroll
    for (int kt = 0; kt < 16; ++kt) {       // agg part, K=512
        int k0 = kt*32 + g*8;
        short8 af = *(const short8*)&arow[k0];
        short8 bf = *(const short8*)&m2row[256 + k0];
        acc = __builtin_amdgcn_mfma_f32_16x16x32_bf16(af, bf, acc, 0,0,0);
    }
    float bb = b2f[o];
    #pragma unroll
    for (int i = 0; i < 4; ++i)
        out[(size_t)(r0 + 4*g + i)*256 + o] = acc[i] + bb;
}

extern "C" void kernel_launch(void* const* d_in, const int* in_sizes, int n_in,
                              void* d_out, int out_size, void* d_ws, size_t ws_size,
                              hipStream_t stream) {
    (void)in_sizes; (void)n_in; (void)out_size; (void)ws_size;
    const float* x    = (const float*)d_in[0];
    // d_in[1] aux_x: unused by reference
    const int*   msk  = (const int*)d_in[2];
    const float* edge = (const float*)d_in[3];
    const float* Wq   = (const float*)d_in[4];
    const float* bq   = (const float*)d_in[5];
    const float* Wk   = (const float*)d_in[6];
    // d_in[7] bk: constant over j -> cancels in softmax
    const float* Wv   = (const float*)d_in[8];
    const float* bv   = (const float*)d_in[9];
    const float* Wp   = (const float*)d_in[10];
    const float* bp   = (const float*)d_in[11];
    float* out = (float*)d_out;
    float* ws  = (float*)d_ws;

    ushort* qkp = (ushort*)(ws + OFF_QKP);
    ushort* agg = (ushort*)(ws + OFF_AGG);
    ushort* M2u = (ushort*)(ws + OFF_M2);
    float*  b2f = ws + OFF_B2;

    k1_proj<<<161, 256, 0, stream>>>(x, Wq, bq, Wk, Wv, bv, Wp, bp, qkp, M2u, b2f);
    k2_attn<<<512, 512, 0, stream>>>(edge, msk, qkp, agg);
    k3_out<<<128, 256, 0, stream>>>(x, agg, M2u, b2f, out);
}

// Round 14
// 21.352 us; speedup vs baseline: 1.4347x; 1.4347x over previous
//
#include <hip/hip_runtime.h>

#define SENT (-3.402823466e38f)

typedef __attribute__((ext_vector_type(8))) short short8;
typedef __attribute__((ext_vector_type(4))) float floatx4;

// ws float offsets
#define OFF_QKP   0         // ushort[512][512]  (qkp bf16, scale baked in)
#define OFF_AGG   131072    // ushort[512][512]  (agg bf16)
#define OFF_VNODE 262144    // float [512][256]

__device__ __forceinline__ ushort f2b(float f) {          // RNE fp32->bf16
    uint u = __float_as_uint(f);
    u += 0x7FFFu + ((u >> 16) & 1u);
    return (ushort)(u >> 16);
}
__device__ __forceinline__ short8 pk8(float4 a, float4 b) {
    short8 r;
    r[0]=(short)f2b(a.x); r[1]=(short)f2b(a.y); r[2]=(short)f2b(a.z); r[3]=(short)f2b(a.w);
    r[4]=(short)f2b(b.x); r[5]=(short)f2b(b.y); r[6]=(short)f2b(b.z); r[7]=(short)f2b(b.w);
    return r;
}

// ---------------- K1: q -> qkp, vnode. MFMA with RAW weights ---------------
// grid 256 = (rt 32 x ct 4 x m 2), 256 thr (4 waves). Block: 16 rows x 64 c.
__global__ __launch_bounds__(256, 4)
void k1_proj(const float* __restrict__ x, const float* __restrict__ Wq,
             const float* __restrict__ Wv, const float* __restrict__ Wk,
             const float* __restrict__ bq, const float* __restrict__ bv,
             float* __restrict__ vnode, ushort* __restrict__ qkp) {
    __shared__ float xL[16][264];   // stride 264 (16B-aligned rows)
    __shared__ float qls[16][66];   // q slice [row][c-local 64]
    int tid = threadIdx.x;
    int w = tid >> 6, lane = tid & 63, g = lane >> 4, r = lane & 15;
    int m  = blockIdx.x & 1;
    int ct = (blockIdx.x >> 1) & 3;
    int rt = blockIdx.x >> 3;
    int r0 = rt*16, c0 = ct*64;

    #pragma unroll
    for (int it = 0; it < 4; ++it) {     // stage x[16][256]
        int fid = (tid + 256*it)*4;
        int rr = fid >> 8, k = fid & 255;
        *(float4*)&xL[rr][k] = *(const float4*)&x[(size_t)(r0+rr)*256 + k];
    }
    __syncthreads();

    int c = c0 + w*16 + r;               // B-frag col (lane&15 = n)
    const float* Wrow = m ? (Wv + (size_t)c*320) : (Wq + (size_t)c*256);
    floatx4 acc = {0.f,0.f,0.f,0.f};
    #pragma unroll
    for (int kt = 0; kt < 8; ++kt) {
        int k0 = kt*32 + g*8;
        short8 af = pk8(*(float4*)&xL[r][k0], *(float4*)&xL[r][k0+4]);
        short8 bf = pk8(*(const float4*)&Wrow[k0], *(const float4*)&Wrow[k0+4]);
        acc = __builtin_amdgcn_mfma_f32_16x16x32_bf16(af, bf, acc, 0,0,0);
    }
    float bb = m ? bv[c] : bq[c];
    if (m) {   // vnode out (D: row=4g+i, col=r)
        #pragma unroll
        for (int i = 0; i < 4; ++i)
            vnode[(size_t)(r0 + 4*g + i)*256 + c] = acc[i] + bb;
    } else {   // q slice -> LDS, then qkp (raw Wk edge cols, coalesced)
        #pragma unroll
        for (int i = 0; i < 4; ++i)
            qls[4*g + i][w*16 + r] = acc[i] + bb;
        __syncthreads();
        int rr = tid >> 4, es = tid & 15;        // row, e-quad
        int h0 = ct*2;
        float a0[4] = {0,0,0,0}, a1[4] = {0,0,0,0};
        const float* wk0 = Wk + (size_t)(h0*32)*320 + 256 + es*4;
        const float* wk1 = Wk + (size_t)((h0+1)*32)*320 + 256 + es*4;
        #pragma unroll 8
        for (int d = 0; d < 32; ++d) {
            float q0 = qls[rr][d];
            float q1 = qls[rr][32 + d];
            float4 w0 = *(const float4*)&wk0[(size_t)d*320];
            float4 w1 = *(const float4*)&wk1[(size_t)d*320];
            a0[0]+=q0*w0.x; a0[1]+=q0*w0.y; a0[2]+=q0*w0.z; a0[3]+=q0*w0.w;
            a1[0]+=q1*w1.x; a1[1]+=q1*w1.y; a1[2]+=q1*w1.z; a1[3]+=q1*w1.w;
        }
        const float s = 0.17677669529663687f;    // 1/sqrt(32)
        ushort4 u0, u1;
        u0.x=f2b(a0[0]*s); u0.y=f2b(a0[1]*s); u0.z=f2b(a0[2]*s); u0.w=f2b(a0[3]*s);
        u1.x=f2b(a1[0]*s); u1.y=f2b(a1[1]*s); u1.z=f2b(a1[2]*s); u1.w=f2b(a1[3]*s);
        size_t base = (size_t)(r0 + rr)*512;
        *(ushort4*)&qkp[base + h0*64 + es*4]     = u0;
        *(ushort4*)&qkp[base + (h0+1)*64 + es*4] = u1;
    }
}

// ---------------- K2: per-row attention, 512 thr ---------------------------
// grid 512, block = one (b,i) row. Logits: wave = j-tile. Softmax: wave = head.
__global__ __launch_bounds__(512, 4)
void k2_attn(const float* __restrict__ edge, const int* __restrict__ msk,
             const ushort* __restrict__ qkp, ushort* __restrict__ aggO) {
    __shared__ ushort edsA[128][72];
    __shared__ ushort qkpL[16][64];
    __shared__ float  attL[8][132];
    __shared__ ushort attT[16][136];
    __shared__ float  mval[128];
    int tid = threadIdx.x;
    int w = tid >> 6, lane = tid & 63, g = lane >> 4, r = lane & 15;
    int row = blockIdx.x;

    float4 ef[4];
    const float* eg = edge + (size_t)row*8192;
    #pragma unroll
    for (int it = 0; it < 4; ++it)
        ef[it] = *(const float4*)(eg + (size_t)(tid + 512*it)*4);

    if (tid < 256) {   // qkp stage (+ zero pad rows 8..15)
        ushort* qf = (ushort*)qkpL;
        *(uint*)&qf[tid*2]        = *(const uint*)&qkp[(size_t)row*512 + tid*2];
        *(uint*)&qf[512 + tid*2]  = 0u;
    }
    if (tid < 128) mval[tid] = (msk[(size_t)row*128 + tid] != 0) ? 1.0f : 0.0f;
    if (tid < 136) {
        #pragma unroll
        for (int hp = 8; hp < 16; ++hp) attT[hp][tid] = 0;
    }
    #pragma unroll
    for (int it = 0; it < 4; ++it) {   // edge -> bf16 LDS
        int fid = (tid + 512*it)*4;
        int j = fid >> 6, e = fid & 63;
        uint lo = (uint)f2b(ef[it].x) | ((uint)f2b(ef[it].y) << 16);
        uint hi = (uint)f2b(ef[it].z) | ((uint)f2b(ef[it].w) << 16);
        *(uint2*)&edsA[j][e] = make_uint2(lo, hi);
    }
    __syncthreads();

    {   // logits MFMA: D[j-local][h]; wave w = j-tile mt
        int mt = w;
        floatx4 acc = {0,0,0,0};
        #pragma unroll
        for (int kt = 0; kt < 2; ++kt) {
            short8 af = *(short8*)&edsA[mt*16 + r][kt*32 + g*8];
            short8 bf = *(short8*)&qkpL[r][kt*32 + g*8];
            acc = __builtin_amdgcn_mfma_f32_16x16x32_bf16(af, bf, acc, 0,0,0);
        }
        if (r < 8) {
            #pragma unroll
            for (int i = 0; i < 4; ++i) {
                int j = mt*16 + 4*g + i;
                attL[r][j] = (mval[j] > 0.5f) ? acc[i] : SENT;
            }
        }
    }
    __syncthreads();

    {   // softmax: wave w = head w
        int h = w;
        float v0 = attL[h][lane];
        float v1 = attL[h][64 + lane];
        float mx = fmaxf(v0, v1);
        #pragma unroll
        for (int off = 32; off >= 1; off >>= 1) mx = fmaxf(mx, __shfl_xor(mx, off));
        float e0 = __expf(v0 - mx), e1 = __expf(v1 - mx);
        float smv = e0 + e1;
        #pragma unroll
        for (int off = 32; off >= 1; off >>= 1) smv += __shfl_xor(smv, off);
        float inv = 1.0f / smv;
        attT[h][lane]      = f2b(e0 * inv);
        attT[h][64 + lane] = f2b(e1 * inv);
    }
    __syncthreads();

    if (w < 4) {   // agg MFMA: D[h][e]; wave w = e-tile
        floatx4 acc = {0,0,0,0};
        #pragma unroll
        for (int kt = 0; kt < 4; ++kt) {
            short8 a2 = *(short8*)&attT[r][kt*32 + g*8];
            short8 b2;
            #pragma unroll
            for (int jj = 0; jj < 8; ++jj)
                b2[jj] = (short)edsA[kt*32 + g*8 + jj][w*16 + r];
            acc = __builtin_amdgcn_mfma_f32_16x16x32_bf16(a2, b2, acc, 0,0,0);
        }
        #pragma unroll
        for (int i = 0; i < 4; ++i) {
            int h = 4*g + i;
            if (h < 8)
                aggO[(size_t)row*512 + h*64 + w*16 + r] = f2b(acc[i]);
        }
    }
}

// ---------------- K3: y + out projection -----------------------------------
// grid 128 = (rt 32 x ob 4), 256 thr. Raw Wv-edge / Wp rows as B-frags.
__global__ __launch_bounds__(256, 2)
void k3_out(const float* __restrict__ vnode, const ushort* __restrict__ aggI,
            const float* __restrict__ Wv, const float* __restrict__ Wp,
            const float* __restrict__ bp, float* __restrict__ out) {
    __shared__ ushort yL[16][264];
    int tid = threadIdx.x;
    int w = tid >> 6, lane = tid & 63, g = lane >> 4, r = lane & 15;
    int rt = blockIdx.x >> 2, ob = blockIdx.x & 3;
    int r0 = rt*16, o0 = ob*64;

    {   // y phase: wave w -> 4 (head, c-subtile) pairs
        #pragma unroll
        for (int pi = 0; pi < 4; ++pi) {
            int p = w*4 + pi, h = p >> 1, ntl = p & 1;
            int c = h*32 + ntl*16 + r;
            floatx4 acc;
            #pragma unroll
            for (int i = 0; i < 4; ++i)
                acc[i] = vnode[(size_t)(r0 + 4*g + i)*256 + c];
            #pragma unroll
            for (int kt = 0; kt < 2; ++kt) {
                short8 af = *(const short8*)&aggI[(size_t)(r0 + r)*512 + h*64 + kt*32 + g*8];
                const float* wr = Wv + (size_t)c*320 + 256 + kt*32 + g*8;
                short8 bf = pk8(*(const float4*)wr, *(const float4*)(wr + 4));
                acc = __builtin_amdgcn_mfma_f32_16x16x32_bf16(af, bf, acc, 0,0,0);
            }
            #pragma unroll
            for (int i = 0; i < 4; ++i)
                yL[4*g + i][c] = f2b(acc[i]);
        }
    }
    __syncthreads();

    {   // out phase: wave w = o-subtile
        int o = o0 + w*16 + r;
        floatx4 acc = {0,0,0,0};
        const float* wr = Wp + (size_t)o*256;
        #pragma unroll
        for (int kt = 0; kt < 8; ++kt) {
            int k0 = kt*32 + g*8;
            short8 af = *(short8*)&yL[r][k0];
            short8 bf = pk8(*(const float4*)&wr[k0], *(const float4*)&wr[k0+4]);
            acc = __builtin_amdgcn_mfma_f32_16x16x32_bf16(af, bf, acc, 0,0,0);
        }
        float bb = bp[o];
        #pragma unroll
        for (int i = 0; i < 4; ++i)
            out[(size_t)(r0 + 4*g + i)*256 + o] = acc[i] + bb;
    }
}

extern "C" void kernel_launch(void* const* d_in, const int* in_sizes, int n_in,
                              void* d_out, int out_size, void* d_ws, size_t ws_size,
                              hipStream_t stream) {
    (void)in_sizes; (void)n_in; (void)out_size; (void)ws_size;
    const float* x    = (const float*)d_in[0];
    // d_in[1] aux_x: unused by reference
    const int*   msk  = (const int*)d_in[2];
    const float* edge = (const float*)d_in[3];
    const float* Wq   = (const float*)d_in[4];
    const float* bq   = (const float*)d_in[5];
    const float* Wk   = (const float*)d_in[6];
    // d_in[7] bk: constant over j -> cancels in softmax
    const float* Wv   = (const float*)d_in[8];
    const float* bv   = (const float*)d_in[9];
    const float* Wp   = (const float*)d_in[10];
    const float* bp   = (const float*)d_in[11];
    float* out = (float*)d_out;
    float* ws  = (float*)d_ws;

    ushort* qkp   = (ushort*)(ws + OFF_QKP);
    ushort* agg   = (ushort*)(ws + OFF_AGG);
    float*  vnode = ws + OFF_VNODE;

    k1_proj<<<256, 256, 0, stream>>>(x, Wq, Wv, Wk, bq, bv, vnode, qkp);
    k2_attn<<<512, 512, 0, stream>>>(edge, msk, qkp, agg);
    k3_out<<<128, 256, 0, stream>>>(vnode, agg, Wv, Wp, bp, out);
}

// Round 15
// 20.207 us; speedup vs baseline: 1.5161x; 1.0567x over previous
//
#include <hip/hip_runtime.h>

#define SENT (-3.402823466e38f)

typedef __attribute__((ext_vector_type(8))) short short8;
typedef __attribute__((ext_vector_type(4))) float floatx4;

// ws float offsets
#define OFF_QKP   0         // ushort[512][512]  (qkp bf16, scale baked in)
#define OFF_AGG   131072    // ushort[512][512]  (agg bf16)
#define OFF_VNODE 262144    // float [512][256]
#define OFF_WPB   393216    // ushort[256][256]  Wp pre-converted bf16
#define OFF_WVEB  425984    // ushort[256][64]   Wv edge cols pre-converted bf16

__device__ __forceinline__ ushort f2b(float f) {          // RNE fp32->bf16
    uint u = __float_as_uint(f);
    u += 0x7FFFu + ((u >> 16) & 1u);
    return (ushort)(u >> 16);
}
__device__ __forceinline__ short8 pk8(float4 a, float4 b) {
    short8 r;
    r[0]=(short)f2b(a.x); r[1]=(short)f2b(a.y); r[2]=(short)f2b(a.z); r[3]=(short)f2b(a.w);
    r[4]=(short)f2b(b.x); r[5]=(short)f2b(b.y); r[6]=(short)f2b(b.z); r[7]=(short)f2b(b.w);
    return r;
}
__device__ __forceinline__ ushort4 cvt4(float4 v) {
    ushort4 u; u.x=f2b(v.x); u.y=f2b(v.y); u.z=f2b(v.z); u.w=f2b(v.w);
    return u;
}

// ---------------- K1: q -> qkp, vnode (MFMA) + weight bf16 pre-conversion --
// grid 276: b<256 main (rt 32 x ct 4 x m 2); b<272 WpB convert; else WvEB.
__global__ __launch_bounds__(256, 4)
void k1_proj(const float* __restrict__ x, const float* __restrict__ Wq,
             const float* __restrict__ Wv, const float* __restrict__ Wk,
             const float* __restrict__ Wp,
             const float* __restrict__ bq, const float* __restrict__ bv,
             float* __restrict__ vnode, ushort* __restrict__ qkp,
             ushort* __restrict__ WpB, ushort* __restrict__ WvEB) {
    __shared__ ushort xLb[16][280];  // bf16 x tile, stride 280 (560B, 2-way ok)
    __shared__ float qls[16][66];    // q slice [row][c-local 64]
    int tid = threadIdx.x;
    int b = blockIdx.x;

    if (b >= 256) {
        if (b < 272) {   // WpB: [256][256] fp32 -> bf16, coalesced stream
            int base = (b - 256)*4096 + tid*16;
            #pragma unroll
            for (int t = 0; t < 4; ++t) {
                float4 v = *(const float4*)&Wp[base + t*4];
                *(ushort4*)&WpB[base + t*4] = cvt4(v);
            }
        } else {         // WvEB: Wv[c][256+e] -> [c][64] bf16
            int base = (b - 272)*4096 + tid*16;
            int c = base >> 6, e = base & 63;
            const float* src = Wv + (size_t)c*320 + 256 + e;
            #pragma unroll
            for (int t = 0; t < 4; ++t) {
                float4 v = *(const float4*)&src[t*4];
                *(ushort4*)&WvEB[base + t*4] = cvt4(v);
            }
        }
        return;
    }

    int w = tid >> 6, lane = tid & 63, g = lane >> 4, r = lane & 15;
    int m  = b & 1;
    int ct = (b >> 1) & 3;
    int rt = b >> 3;
    int r0 = rt*16, c0 = ct*64;

    #pragma unroll
    for (int it = 0; it < 4; ++it) {     // stage x[16][256] -> bf16 LDS
        int fid = (tid + 256*it)*4;
        int rr = fid >> 8, k = fid & 255;
        float4 xv = *(const float4*)&x[(size_t)(r0+rr)*256 + k];
        *(ushort4*)&xLb[rr][k] = cvt4(xv);
    }
    __syncthreads();

    int c = c0 + w*16 + r;               // B-frag col (lane&15 = n)
    const float* Wrow = m ? (Wv + (size_t)c*320) : (Wq + (size_t)c*256);
    floatx4 acc = {0.f,0.f,0.f,0.f};
    #pragma unroll
    for (int kt = 0; kt < 8; ++kt) {
        int k0 = kt*32 + g*8;
        short8 af = *(short8*)&xLb[r][k0];                       // pure LDS read
        short8 bf = pk8(*(const float4*)&Wrow[k0], *(const float4*)&Wrow[k0+4]);
        acc = __builtin_amdgcn_mfma_f32_16x16x32_bf16(af, bf, acc, 0,0,0);
    }
    float bb = m ? bv[c] : bq[c];
    if (m) {   // vnode out (D: row=4g+i, col=r)
        #pragma unroll
        for (int i = 0; i < 4; ++i)
            vnode[(size_t)(r0 + 4*g + i)*256 + c] = acc[i] + bb;
    } else {   // q slice -> LDS, then qkp (raw Wk edge cols, coalesced)
        #pragma unroll
        for (int i = 0; i < 4; ++i)
            qls[4*g + i][w*16 + r] = acc[i] + bb;
        __syncthreads();
        int rr = tid >> 4, es = tid & 15;        // row, e-quad
        int h0 = ct*2;
        float a0[4] = {0,0,0,0}, a1[4] = {0,0,0,0};
        const float* wk0 = Wk + (size_t)(h0*32)*320 + 256 + es*4;
        const float* wk1 = Wk + (size_t)((h0+1)*32)*320 + 256 + es*4;
        #pragma unroll 8
        for (int d = 0; d < 32; ++d) {
            float q0 = qls[rr][d];
            float q1 = qls[rr][32 + d];
            float4 w0 = *(const float4*)&wk0[(size_t)d*320];
            float4 w1 = *(const float4*)&wk1[(size_t)d*320];
            a0[0]+=q0*w0.x; a0[1]+=q0*w0.y; a0[2]+=q0*w0.z; a0[3]+=q0*w0.w;
            a1[0]+=q1*w1.x; a1[1]+=q1*w1.y; a1[2]+=q1*w1.z; a1[3]+=q1*w1.w;
        }
        const float s = 0.17677669529663687f;    // 1/sqrt(32)
        ushort4 u0, u1;
        u0.x=f2b(a0[0]*s); u0.y=f2b(a0[1]*s); u0.z=f2b(a0[2]*s); u0.w=f2b(a0[3]*s);
        u1.x=f2b(a1[0]*s); u1.y=f2b(a1[1]*s); u1.z=f2b(a1[2]*s); u1.w=f2b(a1[3]*s);
        size_t base = (size_t)(r0 + rr)*512;
        *(ushort4*)&qkp[base + h0*64 + es*4]     = u0;
        *(ushort4*)&qkp[base + (h0+1)*64 + es*4] = u1;
    }
}

// ---------------- K2: per-row attention, 512 thr (r12-proven, unchanged) ---
__global__ __launch_bounds__(512, 4)
void k2_attn(const float* __restrict__ edge, const int* __restrict__ msk,
             const ushort* __restrict__ qkp, ushort* __restrict__ aggO) {
    __shared__ ushort edsA[128][72];
    __shared__ ushort qkpL[16][64];
    __shared__ float  attL[8][132];
    __shared__ ushort attT[16][136];
    __shared__ float  mval[128];
    int tid = threadIdx.x;
    int w = tid >> 6, lane = tid & 63, g = lane >> 4, r = lane & 15;
    int row = blockIdx.x;

    float4 ef[4];
    const float* eg = edge + (size_t)row*8192;
    #pragma unroll
    for (int it = 0; it < 4; ++it)
        ef[it] = *(const float4*)(eg + (size_t)(tid + 512*it)*4);

    if (tid < 256) {   // qkp stage (+ zero pad rows 8..15)
        ushort* qf = (ushort*)qkpL;
        *(uint*)&qf[tid*2]        = *(const uint*)&qkp[(size_t)row*512 + tid*2];
        *(uint*)&qf[512 + tid*2]  = 0u;
    }
    if (tid < 128) mval[tid] = (msk[(size_t)row*128 + tid] != 0) ? 1.0f : 0.0f;
    if (tid < 136) {
        #pragma unroll
        for (int hp = 8; hp < 16; ++hp) attT[hp][tid] = 0;
    }
    #pragma unroll
    for (int it = 0; it < 4; ++it) {   // edge -> bf16 LDS
        int fid = (tid + 512*it)*4;
        int j = fid >> 6, e = fid & 63;
        uint lo = (uint)f2b(ef[it].x) | ((uint)f2b(ef[it].y) << 16);
        uint hi = (uint)f2b(ef[it].z) | ((uint)f2b(ef[it].w) << 16);
        *(uint2*)&edsA[j][e] = make_uint2(lo, hi);
    }
    __syncthreads();

    {   // logits MFMA: D[j-local][h]; wave w = j-tile mt
        int mt = w;
        floatx4 acc = {0,0,0,0};
        #pragma unroll
        for (int kt = 0; kt < 2; ++kt) {
            short8 af = *(short8*)&edsA[mt*16 + r][kt*32 + g*8];
            short8 bf = *(short8*)&qkpL[r][kt*32 + g*8];
            acc = __builtin_amdgcn_mfma_f32_16x16x32_bf16(af, bf, acc, 0,0,0);
        }
        if (r < 8) {
            #pragma unroll
            for (int i = 0; i < 4; ++i) {
                int j = mt*16 + 4*g + i;
                attL[r][j] = (mval[j] > 0.5f) ? acc[i] : SENT;
            }
        }
    }
    __syncthreads();

    {   // softmax: wave w = head w
        int h = w;
        float v0 = attL[h][lane];
        float v1 = attL[h][64 + lane];
        float mx = fmaxf(v0, v1);
        #pragma unroll
        for (int off = 32; off >= 1; off >>= 1) mx = fmaxf(mx, __shfl_xor(mx, off));
        float e0 = __expf(v0 - mx), e1 = __expf(v1 - mx);
        float smv = e0 + e1;
        #pragma unroll
        for (int off = 32; off >= 1; off >>= 1) smv += __shfl_xor(smv, off);
        float inv = 1.0f / smv;
        attT[h][lane]      = f2b(e0 * inv);
        attT[h][64 + lane] = f2b(e1 * inv);
    }
    __syncthreads();

    if (w < 4) {   // agg MFMA: D[h][e]; wave w = e-tile
        floatx4 acc = {0,0,0,0};
        #pragma unroll
        for (int kt = 0; kt < 4; ++kt) {
            short8 a2 = *(short8*)&attT[r][kt*32 + g*8];
            short8 b2;
            #pragma unroll
            for (int jj = 0; jj < 8; ++jj)
                b2[jj] = (short)edsA[kt*32 + g*8 + jj][w*16 + r];
            acc = __builtin_amdgcn_mfma_f32_16x16x32_bf16(a2, b2, acc, 0,0,0);
        }
        #pragma unroll
        for (int i = 0; i < 4; ++i) {
            int h = 4*g + i;
            if (h < 8)
                aggO[(size_t)row*512 + h*64 + w*16 + r] = f2b(acc[i]);
        }
    }
}

// ---------------- K3: y + out projection (pre-converted bf16 weights) ------
// grid 128 = (rt 32 x ob 4), 256 thr. B-frags: single short8 loads.
__global__ __launch_bounds__(256, 2)
void k3_out(const float* __restrict__ vnode, const ushort* __restrict__ aggI,
            const ushort* __restrict__ WvEB, const ushort* __restrict__ WpB,
            const float* __restrict__ bp, float* __restrict__ out) {
    __shared__ ushort yL[16][264];
    int tid = threadIdx.x;
    int w = tid >> 6, lane = tid & 63, g = lane >> 4, r = lane & 15;
    int rt = blockIdx.x >> 2, ob = blockIdx.x & 3;
    int r0 = rt*16, o0 = ob*64;

    {   // y phase: wave w -> 4 (head, c-subtile) pairs
        #pragma unroll
        for (int pi = 0; pi < 4; ++pi) {
            int p = w*4 + pi, h = p >> 1, ntl = p & 1;
            int c = h*32 + ntl*16 + r;
            floatx4 acc;
            #pragma unroll
            for (int i = 0; i < 4; ++i)
                acc[i] = vnode[(size_t)(r0 + 4*g + i)*256 + c];
            #pragma unroll
            for (int kt = 0; kt < 2; ++kt) {
                short8 af = *(const short8*)&aggI[(size_t)(r0 + r)*512 + h*64 + kt*32 + g*8];
                short8 bf = *(const short8*)&WvEB[(size_t)c*64 + kt*32 + g*8];
                acc = __builtin_amdgcn_mfma_f32_16x16x32_bf16(af, bf, acc, 0,0,0);
            }
            #pragma unroll
            for (int i = 0; i < 4; ++i)
                yL[4*g + i][c] = f2b(acc[i]);
        }
    }
    __syncthreads();

    {   // out phase: wave w = o-subtile
        int o = o0 + w*16 + r;
        floatx4 acc = {0,0,0,0};
        const ushort* wr = WpB + (size_t)o*256;
        #pragma unroll
        for (int kt = 0; kt < 8; ++kt) {
            int k0 = kt*32 + g*8;
            short8 af = *(short8*)&yL[r][k0];
            short8 bf = *(const short8*)&wr[k0];
            acc = __builtin_amdgcn_mfma_f32_16x16x32_bf16(af, bf, acc, 0,0,0);
        }
        float bb = bp[o];
        #pragma unroll
        for (int i = 0; i < 4; ++i)
            out[(size_t)(r0 + 4*g + i)*256 + o] = acc[i] + bb;
    }
}

extern "C" void kernel_launch(void* const* d_in, const int* in_sizes, int n_in,
                              void* d_out, int out_size, void* d_ws, size_t ws_size,
                              hipStream_t stream) {
    (void)in_sizes; (void)n_in; (void)out_size; (void)ws_size;
    const float* x    = (const float*)d_in[0];
    // d_in[1] aux_x: unused by reference
    const int*   msk  = (const int*)d_in[2];
    const float* edge = (const float*)d_in[3];
    const float* Wq   = (const float*)d_in[4];
    const float* bq   = (const float*)d_in[5];
    const float* Wk   = (const float*)d_in[6];
    // d_in[7] bk: constant over j -> cancels in softmax
    const float* Wv   = (const float*)d_in[8];
    const float* bv   = (const float*)d_in[9];
    const float* Wp   = (const float*)d_in[10];
    const float* bp   = (const float*)d_in[11];
    float* out = (float*)d_out;
    float* ws  = (float*)d_ws;

    ushort* qkp   = (ushort*)(ws + OFF_QKP);
    ushort* agg   = (ushort*)(ws + OFF_AGG);
    float*  vnode = ws + OFF_VNODE;
    ushort* WpB   = (ushort*)(ws + OFF_WPB);
    ushort* WvEB  = (ushort*)(ws + OFF_WVEB);

    k1_proj<<<276, 256, 0, stream>>>(x, Wq, Wv, Wk, Wp, bq, bv, vnode, qkp, WpB, WvEB);
    k2_attn<<<512, 512, 0, stream>>>(edge, msk, qkp, agg);
    k3_out<<<128, 256, 0, stream>>>(vnode, agg, WvEB, WpB, bp, out);
}

// Round 16
// 20.173 us; speedup vs baseline: 1.5186x; 1.0017x over previous
//
#include <hip/hip_runtime.h>
#include <hip/hip_bf16.h>

#define SENT (-3.402823466e38f)

typedef __attribute__((ext_vector_type(8))) short short8;
typedef __attribute__((ext_vector_type(4))) float floatx4;

// ws float offsets
#define OFF_QKP   0         // ushort[512][512]  (qkp bf16, scale baked in)
#define OFF_AGG   131072    // ushort[512][512]  (agg bf16)
#define OFF_VNODE 262144    // float [512][256]
#define OFF_WPB   393216    // ushort[256][256]  Wp pre-converted bf16
#define OFF_WVEB  425984    // ushort[256][64]   Wv edge cols pre-converted bf16

__device__ __forceinline__ ushort f2b(float f) {          // RNE fp32->bf16
    uint u = __float_as_uint(f);
    u += 0x7FFFu + ((u >> 16) & 1u);
    return (ushort)(u >> 16);
}
__device__ __forceinline__ uint f2b2(float a, float b) {  // packed RNE pair
    __hip_bfloat162 h = __float22bfloat162_rn(make_float2(a, b));
    return *reinterpret_cast<uint*>(&h);                  // v_cvt_pk_bf16_f32
}
__device__ __forceinline__ short8 pk8(float4 a, float4 b) {
    union { short8 s; uint u[4]; } r;
    r.u[0] = f2b2(a.x, a.y);
    r.u[1] = f2b2(a.z, a.w);
    r.u[2] = f2b2(b.x, b.y);
    r.u[3] = f2b2(b.z, b.w);
    return r.s;
}
__device__ __forceinline__ ushort4 cvt4(float4 v) {
    union { ushort4 u4; uint u[2]; } r;
    r.u[0] = f2b2(v.x, v.y);
    r.u[1] = f2b2(v.z, v.w);
    return r.u4;
}

// ---------------- K1: q -> qkp, vnode (MFMA) + weight bf16 pre-conversion --
// grid 276: b<256 main (rt 32 x ct 4 x m 2); b<272 WpB convert; else WvEB.
__global__ __launch_bounds__(256, 4)
void k1_proj(const float* __restrict__ x, const float* __restrict__ Wq,
             const float* __restrict__ Wv, const float* __restrict__ Wk,
             const float* __restrict__ Wp,
             const float* __restrict__ bq, const float* __restrict__ bv,
             float* __restrict__ vnode, ushort* __restrict__ qkp,
             ushort* __restrict__ WpB, ushort* __restrict__ WvEB) {
    __shared__ ushort xLb[16][280];  // bf16 x tile, stride 280 (560B, 2-way ok)
    __shared__ float qls[16][66];    // q slice [row][c-local 64]
    int tid = threadIdx.x;
    int b = blockIdx.x;

    if (b >= 256) {
        if (b < 272) {   // WpB: [256][256] fp32 -> bf16, coalesced stream
            int base = (b - 256)*4096 + tid*16;
            #pragma unroll
            for (int t = 0; t < 4; ++t) {
                float4 v = *(const float4*)&Wp[base + t*4];
                *(ushort4*)&WpB[base + t*4] = cvt4(v);
            }
        } else {         // WvEB: Wv[c][256+e] -> [c][64] bf16
            int base = (b - 272)*4096 + tid*16;
            int c = base >> 6, e = base & 63;
            const float* src = Wv + (size_t)c*320 + 256 + e;
            #pragma unroll
            for (int t = 0; t < 4; ++t) {
                float4 v = *(const float4*)&src[t*4];
                *(ushort4*)&WvEB[base + t*4] = cvt4(v);
            }
        }
        return;
    }

    int w = tid >> 6, lane = tid & 63, g = lane >> 4, r = lane & 15;
    int m  = b & 1;
    int ct = (b >> 1) & 3;
    int rt = b >> 3;
    int r0 = rt*16, c0 = ct*64;

    #pragma unroll
    for (int it = 0; it < 4; ++it) {     // stage x[16][256] -> bf16 LDS
        int fid = (tid + 256*it)*4;
        int rr = fid >> 8, k = fid & 255;
        float4 xv = *(const float4*)&x[(size_t)(r0+rr)*256 + k];
        *(ushort4*)&xLb[rr][k] = cvt4(xv);
    }
    __syncthreads();

    int c = c0 + w*16 + r;               // B-frag col (lane&15 = n)
    const float* Wrow = m ? (Wv + (size_t)c*320) : (Wq + (size_t)c*256);
    floatx4 acc = {0.f,0.f,0.f,0.f};
    #pragma unroll
    for (int kt = 0; kt < 8; ++kt) {
        int k0 = kt*32 + g*8;
        short8 af = *(short8*)&xLb[r][k0];                       // pure LDS read
        short8 bf = pk8(*(const float4*)&Wrow[k0], *(const float4*)&Wrow[k0+4]);
        acc = __builtin_amdgcn_mfma_f32_16x16x32_bf16(af, bf, acc, 0,0,0);
    }
    float bb = m ? bv[c] : bq[c];
    if (m) {   // vnode out (D: row=4g+i, col=r)
        #pragma unroll
        for (int i = 0; i < 4; ++i)
            vnode[(size_t)(r0 + 4*g + i)*256 + c] = acc[i] + bb;
    } else {   // q slice -> LDS, then qkp (raw Wk edge cols, coalesced)
        #pragma unroll
        for (int i = 0; i < 4; ++i)
            qls[4*g + i][w*16 + r] = acc[i] + bb;
        __syncthreads();
        int rr = tid >> 4, es = tid & 15;        // row, e-quad
        int h0 = ct*2;
        float a0[4] = {0,0,0,0}, a1[4] = {0,0,0,0};
        const float* wk0 = Wk + (size_t)(h0*32)*320 + 256 + es*4;
        const float* wk1 = Wk + (size_t)((h0+1)*32)*320 + 256 + es*4;
        #pragma unroll 8
        for (int d = 0; d < 32; ++d) {
            float q0 = qls[rr][d];
            float q1 = qls[rr][32 + d];
            float4 w0 = *(const float4*)&wk0[(size_t)d*320];
            float4 w1 = *(const float4*)&wk1[(size_t)d*320];
            a0[0]+=q0*w0.x; a0[1]+=q0*w0.y; a0[2]+=q0*w0.z; a0[3]+=q0*w0.w;
            a1[0]+=q1*w1.x; a1[1]+=q1*w1.y; a1[2]+=q1*w1.z; a1[3]+=q1*w1.w;
        }
        const float s = 0.17677669529663687f;    // 1/sqrt(32)
        float4 v0 = make_float4(a0[0]*s, a0[1]*s, a0[2]*s, a0[3]*s);
        float4 v1 = make_float4(a1[0]*s, a1[1]*s, a1[2]*s, a1[3]*s);
        size_t base = (size_t)(r0 + rr)*512;
        *(ushort4*)&qkp[base + h0*64 + es*4]     = cvt4(v0);
        *(ushort4*)&qkp[base + (h0+1)*64 + es*4] = cvt4(v1);
    }
}

// ---------------- K2: per-row attention, 512 thr (r12-proven structure) ----
__global__ __launch_bounds__(512, 4)
void k2_attn(const float* __restrict__ edge, const int* __restrict__ msk,
             const ushort* __restrict__ qkp, ushort* __restrict__ aggO) {
    __shared__ ushort edsA[128][72];
    __shared__ ushort qkpL[16][64];
    __shared__ float  attL[8][132];
    __shared__ ushort attT[16][136];
    __shared__ float  mval[128];
    int tid = threadIdx.x;
    int w = tid >> 6, lane = tid & 63, g = lane >> 4, r = lane & 15;
    int row = blockIdx.x;

    float4 ef[4];
    const float* eg = edge + (size_t)row*8192;
    #pragma unroll
    for (int it = 0; it < 4; ++it)
        ef[it] = *(const float4*)(eg + (size_t)(tid + 512*it)*4);

    if (tid < 256) {   // qkp stage (+ zero pad rows 8..15)
        ushort* qf = (ushort*)qkpL;
        *(uint*)&qf[tid*2]        = *(const uint*)&qkp[(size_t)row*512 + tid*2];
        *(uint*)&qf[512 + tid*2]  = 0u;
    }
    if (tid < 128) mval[tid] = (msk[(size_t)row*128 + tid] != 0) ? 1.0f : 0.0f;
    if (tid < 136) {
        #pragma unroll
        for (int hp = 8; hp < 16; ++hp) attT[hp][tid] = 0;
    }
    #pragma unroll
    for (int it = 0; it < 4; ++it) {   // edge -> bf16 LDS (packed cvt)
        int fid = (tid + 512*it)*4;
        int j = fid >> 6, e = fid & 63;
        uint lo = f2b2(ef[it].x, ef[it].y);
        uint hi = f2b2(ef[it].z, ef[it].w);
        *(uint2*)&edsA[j][e] = make_uint2(lo, hi);
    }
    __syncthreads();

    {   // logits MFMA: D[j-local][h]; wave w = j-tile mt
        int mt = w;
        floatx4 acc = {0,0,0,0};
        #pragma unroll
        for (int kt = 0; kt < 2; ++kt) {
            short8 af = *(short8*)&edsA[mt*16 + r][kt*32 + g*8];
            short8 bf = *(short8*)&qkpL[r][kt*32 + g*8];
            acc = __builtin_amdgcn_mfma_f32_16x16x32_bf16(af, bf, acc, 0,0,0);
        }
        if (r < 8) {
            #pragma unroll
            for (int i = 0; i < 4; ++i) {
                int j = mt*16 + 4*g + i;
                attL[r][j] = (mval[j] > 0.5f) ? acc[i] : SENT;
            }
        }
    }
    __syncthreads();

    {   // softmax: wave w = head w
        int h = w;
        float v0 = attL[h][lane];
        float v1 = attL[h][64 + lane];
        float mx = fmaxf(v0, v1);
        #pragma unroll
        for (int off = 32; off >= 1; off >>= 1) mx = fmaxf(mx, __shfl_xor(mx, off));
        float e0 = __expf(v0 - mx), e1 = __expf(v1 - mx);
        float smv = e0 + e1;
        #pragma unroll
        for (int off = 32; off >= 1; off >>= 1) smv += __shfl_xor(smv, off);
        float inv = 1.0f / smv;
        attT[h][lane]      = f2b(e0 * inv);
        attT[h][64 + lane] = f2b(e1 * inv);
    }
    __syncthreads();

    if (w < 4) {   // agg MFMA: D[h][e]; wave w = e-tile
        floatx4 acc = {0,0,0,0};
        #pragma unroll
        for (int kt = 0; kt < 4; ++kt) {
            short8 a2 = *(short8*)&attT[r][kt*32 + g*8];
            short8 b2;
            #pragma unroll
            for (int jj = 0; jj < 8; ++jj)
                b2[jj] = (short)edsA[kt*32 + g*8 + jj][w*16 + r];
            acc = __builtin_amdgcn_mfma_f32_16x16x32_bf16(a2, b2, acc, 0,0,0);
        }
        #pragma unroll
        for (int i = 0; i < 4; ++i) {
            int h = 4*g + i;
            if (h < 8)
                aggO[(size_t)row*512 + h*64 + w*16 + r] = f2b(acc[i]);
        }
    }
}

// ---------------- K3: y + out projection (pre-converted bf16 weights) ------
// grid 128 = (rt 32 x ob 4), 256 thr. B-frags: single short8 loads.
__global__ __launch_bounds__(256, 2)
void k3_out(const float* __restrict__ vnode, const ushort* __restrict__ aggI,
            const ushort* __restrict__ WvEB, const ushort* __restrict__ WpB,
            const float* __restrict__ bp, float* __restrict__ out) {
    __shared__ ushort yL[16][264];
    int tid = threadIdx.x;
    int w = tid >> 6, lane = tid & 63, g = lane >> 4, r = lane & 15;
    int rt = blockIdx.x >> 2, ob = blockIdx.x & 3;
    int r0 = rt*16, o0 = ob*64;

    {   // y phase: wave w -> 4 (head, c-subtile) pairs
        #pragma unroll
        for (int pi = 0; pi < 4; ++pi) {
            int p = w*4 + pi, h = p >> 1, ntl = p & 1;
            int c = h*32 + ntl*16 + r;
            floatx4 acc;
            #pragma unroll
            for (int i = 0; i < 4; ++i)
                acc[i] = vnode[(size_t)(r0 + 4*g + i)*256 + c];
            #pragma unroll
            for (int kt = 0; kt < 2; ++kt) {
                short8 af = *(const short8*)&aggI[(size_t)(r0 + r)*512 + h*64 + kt*32 + g*8];
                short8 bf = *(const short8*)&WvEB[(size_t)c*64 + kt*32 + g*8];
                acc = __builtin_amdgcn_mfma_f32_16x16x32_bf16(af, bf, acc, 0,0,0);
            }
            #pragma unroll
            for (int i = 0; i < 4; ++i)
                yL[4*g + i][c] = f2b(acc[i]);
        }
    }
    __syncthreads();

    {   // out phase: wave w = o-subtile
        int o = o0 + w*16 + r;
        floatx4 acc = {0,0,0,0};
        const ushort* wr = WpB + (size_t)o*256;
        #pragma unroll
        for (int kt = 0; kt < 8; ++kt) {
            int k0 = kt*32 + g*8;
            short8 af = *(short8*)&yL[r][k0];
            short8 bf = *(const short8*)&wr[k0];
            acc = __builtin_amdgcn_mfma_f32_16x16x32_bf16(af, bf, acc, 0,0,0);
        }
        float bb = bp[o];
        #pragma unroll
        for (int i = 0; i < 4; ++i)
            out[(size_t)(r0 + 4*g + i)*256 + o] = acc[i] + bb;
    }
}

extern "C" void kernel_launch(void* const* d_in, const int* in_sizes, int n_in,
                              void* d_out, int out_size, void* d_ws, size_t ws_size,
                              hipStream_t stream) {
    (void)in_sizes; (void)n_in; (void)out_size; (void)ws_size;
    const float* x    = (const float*)d_in[0];
    // d_in[1] aux_x: unused by reference
    const int*   msk  = (const int*)d_in[2];
    const float* edge = (const float*)d_in[3];
    const float* Wq   = (const float*)d_in[4];
    const float* bq   = (const float*)d_in[5];
    const float* Wk   = (const float*)d_in[6];
    // d_in[7] bk: constant over j -> cancels in softmax
    const float* Wv   = (const float*)d_in[8];
    const float* bv   = (const float*)d_in[9];
    const float* Wp   = (const float*)d_in[10];
    const float* bp   = (const float*)d_in[11];
    float* out = (float*)d_out;
    float* ws  = (float*)d_ws;

    ushort* qkp   = (ushort*)(ws + OFF_QKP);
    ushort* agg   = (ushort*)(ws + OFF_AGG);
    float*  vnode = ws + OFF_VNODE;
    ushort* WpB   = (ushort*)(ws + OFF_WPB);
    ushort* WvEB  = (ushort*)(ws + OFF_WVEB);

    k1_proj<<<276, 256, 0, stream>>>(x, Wq, Wv, Wk, Wp, bq, bv, vnode, qkp, WpB, WvEB);
    k2_attn<<<512, 512, 0, stream>>>(edge, msk, qkp, agg);
    k3_out<<<128, 256, 0, stream>>>(vnode, agg, WvEB, WpB, bp, out);
}